// Round 1
// baseline (299.212 us; speedup 1.0000x reference)
//
#include <hip/hip_runtime.h>

typedef unsigned short u16;
typedef unsigned int   u32;

typedef __bf16 bf16x8_t __attribute__((ext_vector_type(8)));
typedef bf16x8_t bf16x8 __attribute__((may_alias));
typedef float f32x4_t __attribute__((ext_vector_type(4)));
typedef f32x4_t f32x4 __attribute__((may_alias));
typedef u32 u32x4_t __attribute__((ext_vector_type(4)));
typedef u32x4_t u32x4 __attribute__((may_alias));
typedef u32 u32x2_t __attribute__((ext_vector_type(2)));
typedef u32x2_t u32x2 __attribute__((may_alias));

__device__ __forceinline__ u16 f2b(float f) {        // RNE via hw cvt
  __bf16 h = (__bf16)f; u16 u; __builtin_memcpy(&u, &h, 2); return u;
}
__device__ __forceinline__ float b2f(u16 u) {
  u32 i = ((u32)u) << 16; float f; __builtin_memcpy(&f, &i, 4); return f;
}
__device__ __forceinline__ bf16x8_t cvt8(const float* p) {
  f32x4_t a = *(const f32x4*)p;
  f32x4_t b = *(const f32x4*)(p + 4);
  bf16x8_t v;
  v[0]=(__bf16)a[0]; v[1]=(__bf16)a[1]; v[2]=(__bf16)a[2]; v[3]=(__bf16)a[3];
  v[4]=(__bf16)b[0]; v[5]=(__bf16)b[1]; v[6]=(__bf16)b[2]; v[7]=(__bf16)b[3];
  return v;
}
// async global->LDS, 16B/lane (proper addrspacecast)
typedef __attribute__((address_space(1))) const void* as1cv;
typedef __attribute__((address_space(3))) void* as3v;
__device__ __forceinline__ void gld16(const u16* g, u16* l) {
  __builtin_amdgcn_global_load_lds((as1cv)g, (as3v)l, 16, 0, 0);
}

#define EPS 1.1920929e-07f

// ---------------------------------------------------------------------------
// cvt_pack: x (nx f32) + Wq|Wk|Wv|Wo (1M f32 each) -> bf16 blob (r10)
// ---------------------------------------------------------------------------
#define WSZ (1024 * 1024)
__global__ __launch_bounds__(256) void cvt_pack(
    const float* __restrict__ x, const float* __restrict__ wq,
    const float* __restrict__ wk, const float* __restrict__ wv,
    const float* __restrict__ wo, u16* __restrict__ dst, int nx)
{
  int idx4 = blockIdx.x * 256 + threadIdx.x;
  const int total4 = (nx + 4 * WSZ) >> 2;
  for (; idx4 < total4; idx4 += gridDim.x * 256) {
    int i = idx4 << 2;
    const float* src;
    if (i < nx) src = x + i;
    else {
      int o = i - nx;
      if      (o <     WSZ) src = wq + o;
      else if (o < 2 * WSZ) src = wk + o - WSZ;
      else if (o < 3 * WSZ) src = wv + o - 2 * WSZ;
      else                  src = wo + o - 3 * WSZ;
    }
    f32x4_t v = *(const f32x4*)src;
    u32x2_t p;
    p[0] = (u32)f2b(v[0]) | ((u32)f2b(v[1]) << 16);
    p[1] = (u32)f2b(v[2]) | ((u32)f2b(v[3]) << 16);
    *(u32x2*)(dst + i) = p;
  }
}

// ---------------------------------------------------------------------------
// gemm_bt2 (r10, unchanged): m97 structure + fused RMSNorm epilogue.
// ---------------------------------------------------------------------------
#define BK 32
template<int NORM, int CF32>
__global__ __launch_bounds__(256, 2) void gemm_bt2(
    const u16* __restrict__ A, const u16* __restrict__ Bm,
    const float* __restrict__ bias0, const float* __restrict__ bias1, const float* __restrict__ bias2,
    const float* __restrict__ qn, const float* __restrict__ kn,
    void* __restrict__ C, int M, int K, int ldc)
{
  __shared__ alignas(16) u16 As[128 * BK];
  __shared__ alignas(16) u16 Bs[128 * BK];
  const int t = threadIdx.x;
  const int lane = t & 63, wave = t >> 6;
  const int quad = lane >> 4, col = lane & 15;
  const int m0 = blockIdx.x * 128, n0 = blockIdx.y * 128;
  const int seg = n0 >> 10, nl0 = n0 & 1023;
  const float* bias = seg == 0 ? bias0 : (seg == 1 ? bias1 : bias2);
  const int wm = (wave >> 1) * 64, wn = (wave & 1) * 64;

  const int lrow = t >> 2;
  const int lcol = (t & 3) * 8;
  const u16* ga0 = A  + (size_t)(m0 + lrow) * K + lcol;
  const u16* ga1 = A  + (size_t)(m0 + 64 + lrow) * K + lcol;
  const u16* gb0 = Bm + (size_t)(n0 + lrow) * K + lcol;
  const u16* gb1 = Bm + (size_t)(n0 + 64 + lrow) * K + lcol;
  u16* lA0 = As + t * 8;
  u16* lA1 = As + 64 * BK + t * 8;
  u16* lB0 = Bs + t * 8;
  u16* lB1 = Bs + 64 * BK + t * 8;

  f32x4_t acc[4][4] = {};
  for (int k0 = 0; k0 < K; k0 += BK) {
    __syncthreads();
    gld16(ga0 + k0, lA0);
    gld16(ga1 + k0, lA1);
    gld16(gb0 + k0, lB0);
    gld16(gb1 + k0, lB1);
    __syncthreads();
    bf16x8 af[4], bfr[4];
#pragma unroll
    for (int i = 0; i < 4; ++i) {
      af[i]  = *(const bf16x8*)(As + (wm + i * 16 + col) * BK + quad * 8);
      bfr[i] = *(const bf16x8*)(Bs + (wn + i * 16 + col) * BK + quad * 8);
    }
#pragma unroll
    for (int i = 0; i < 4; ++i)
#pragma unroll
      for (int j = 0; j < 4; ++j)
        acc[i][j] = __builtin_amdgcn_mfma_f32_16x16x32_bf16(af[i], bfr[j], acc[i][j], 0, 0, 0);
  }

  float bz[4], wz[4];
#pragma unroll
  for (int j = 0; j < 4; ++j) {
    bz[j] = bias[nl0 + wn + j * 16 + col];
    if (NORM) wz[j] = (seg == 0 ? qn : kn)[j * 16 + col];
  }
  const bool donorm = NORM && seg < 2;
#pragma unroll
  for (int i = 0; i < 4; ++i) {
#pragma unroll
    for (int rr = 0; rr < 4; ++rr) {
      int gm = m0 + wm + i * 16 + quad * 4 + rr;
      float v[4];
#pragma unroll
      for (int j = 0; j < 4; ++j) v[j] = acc[i][j][rr] + bz[j];
      if (donorm) {
        float ss = v[0]*v[0] + v[1]*v[1] + v[2]*v[2] + v[3]*v[3];
        ss += __shfl_xor(ss, 1);
        ss += __shfl_xor(ss, 2);
        ss += __shfl_xor(ss, 4);
        ss += __shfl_xor(ss, 8);
        float sc = rsqrtf(ss * (1.0f / 64.0f) + EPS);
#pragma unroll
        for (int j = 0; j < 4; ++j) v[j] *= sc * wz[j];
      }
      if (gm < M) {
#pragma unroll
        for (int j = 0; j < 4; ++j) {
          int gn = n0 + wn + j * 16 + col;
          if (CF32) ((float*)C)[(size_t)gm * ldc + gn] = v[j];
          else      ((u16*)C)[(size_t)gm * ldc + gn] = f2b(v[j]);
        }
      }
    }
  }
}

// ---------------------------------------------------------------------------
// FALLBACK tier kernels (r9, unchanged)
// ---------------------------------------------------------------------------
template<int AF32, int CF32>
__global__ __launch_bounds__(256, 2) void gemm_bt(
    const void* __restrict__ Av,
    const float* __restrict__ B0, const float* __restrict__ B1, const float* __restrict__ B2,
    const float* __restrict__ bias0, const float* __restrict__ bias1, const float* __restrict__ bias2,
    void* __restrict__ C, int M, int K, int ldc)
{
  __shared__ alignas(16) u16 As[128 * BK];
  __shared__ alignas(16) u16 Bs[128 * BK];
  const int t = threadIdx.x;
  const int lane = t & 63, wave = t >> 6;
  const int quad = lane >> 4, col = lane & 15;
  const int m0 = blockIdx.x * 128, n0 = blockIdx.y * 128;
  const int seg = n0 >> 10;
  const float* B    = seg == 0 ? B0    : (seg == 1 ? B1    : B2);
  const float* bias = seg == 0 ? bias0 : (seg == 1 ? bias1 : bias2);
  const int nl0 = n0 & 1023;
  const int wm = (wave >> 1) * 64, wn = (wave & 1) * 64;
  const int lrow = t >> 2;
  const int lcol = (t & 3) * 8;
  int ar0 = m0 + lrow;      if (ar0 >= M) ar0 = M - 1;
  int ar1 = m0 + 64 + lrow; if (ar1 >= M) ar1 = M - 1;
  const float* bp0 = B + (size_t)(nl0 + lrow) * K + lcol;
  const float* bp1 = B + (size_t)(nl0 + 64 + lrow) * K + lcol;
  const float* apf0 = (const float*)Av + (size_t)ar0 * K + lcol;
  const float* apf1 = (const float*)Av + (size_t)ar1 * K + lcol;
  const u16*   aph0 = (const u16*)Av   + (size_t)ar0 * K + lcol;
  const u16*   aph1 = (const u16*)Av   + (size_t)ar1 * K + lcol;
  u16* lA0 = As + t * 8;
  u16* lA1 = As + 64 * BK + t * 8;
  u16* lB0 = Bs + t * 8;
  u16* lB1 = Bs + 64 * BK + t * 8;

  f32x4_t acc[4][4] = {};
  for (int k0 = 0; k0 < K; k0 += BK) {
    bf16x8_t va0, va1, vb0, vb1;
    if (AF32) { va0 = cvt8(apf0 + k0); va1 = cvt8(apf1 + k0); }
    else {
      u32x4_t r0 = *(const u32x4*)(aph0 + k0);
      u32x4_t r1 = *(const u32x4*)(aph1 + k0);
      __builtin_memcpy(&va0, &r0, 16);
      __builtin_memcpy(&va1, &r1, 16);
    }
    vb0 = cvt8(bp0 + k0);
    vb1 = cvt8(bp1 + k0);
    __syncthreads();
    *(bf16x8*)lA0 = va0; *(bf16x8*)lA1 = va1;
    *(bf16x8*)lB0 = vb0; *(bf16x8*)lB1 = vb1;
    __syncthreads();
    bf16x8 af[4], bfr[4];
#pragma unroll
    for (int i = 0; i < 4; ++i) {
      af[i]  = *(const bf16x8*)(As + (wm + i * 16 + col) * BK + quad * 8);
      bfr[i] = *(const bf16x8*)(Bs + (wn + i * 16 + col) * BK + quad * 8);
    }
#pragma unroll
    for (int i = 0; i < 4; ++i)
#pragma unroll
      for (int j = 0; j < 4; ++j)
        acc[i][j] = __builtin_amdgcn_mfma_f32_16x16x32_bf16(af[i], bfr[j], acc[i][j], 0, 0, 0);
  }
#pragma unroll
  for (int j = 0; j < 4; ++j) {
    int gn = n0 + wn + j * 16 + col;
    float bz = bias[nl0 + wn + j * 16 + col];
#pragma unroll
    for (int i = 0; i < 4; ++i) {
#pragma unroll
      for (int rr = 0; rr < 4; ++rr) {
        int gm = m0 + wm + i * 16 + quad * 4 + rr;
        if (gm < M) {
          float v = acc[i][j][rr] + bz;
          if (CF32) ((float*)C)[(size_t)gm * ldc + gn] = v;
          else      ((u16*)C)[(size_t)gm * ldc + gn] = f2b(v);
        }
      }
    }
  }
}

__global__ __launch_bounds__(256) void rmsnorm_qk(
    u16* __restrict__ qkv, const float* __restrict__ qn, const float* __restrict__ kn, int T)
{
  int gid = blockIdx.x * 256 + threadIdx.x;
  int row = gid >> 4, sub = gid & 15;
  if (row >= 2 * T * 16) return;
  int which = row >= T * 16;
  int r = which ? row - T * 16 : row;
  int tok = r >> 4, head = r & 15;
  u16* p = qkv + (size_t)tok * 3072 + which * 1024 + head * 64 + sub * 4;
  u16 d0 = p[0], d1 = p[1], d2 = p[2], d3 = p[3];
  float f0 = b2f(d0), f1 = b2f(d1), f2v = b2f(d2), f3 = b2f(d3);
  float ss = f0 * f0 + f1 * f1 + f2v * f2v + f3 * f3;
  ss += __shfl_xor(ss, 1);
  ss += __shfl_xor(ss, 2);
  ss += __shfl_xor(ss, 4);
  ss += __shfl_xor(ss, 8);
  float sc = rsqrtf(ss * (1.0f / 64.0f) + EPS);
  const float* w = which ? kn : qn;
  p[0] = f2b(f0 * sc * w[sub * 4 + 0]);
  p[1] = f2b(f1 * sc * w[sub * 4 + 1]);
  p[2] = f2b(f2v * sc * w[sub * 4 + 2]);
  p[3] = f2b(f3 * sc * w[sub * 4 + 3]);
}

// ---------------------------------------------------------------------------
// Flash attention v5: v4 structure, but L (softmax denominator) is now
// accumulated in registers from the same masked bf16 P values each lane
// produces, instead of 4 extra MFMAs/iter against a ones-row of V.
//   - removes 4/36 MFMA per wave-iter (matrix pipe)
//   - removes 2 b128 LDS reads per wave-iter + the ones-row init (LDS pipe,
//     which the per-CU arithmetic says is the binding resource at 16 waves/CU)
//   - cross-lane reduce (shfl_xor over the 16 lanes sharing a quad) deferred
//     to the epilogue: 4 shfl per row ONCE, not per KV tile.
// L sums b2f(pe*) — bit-identical P values to what the PV numerator reads
// from LDS — so numerics match v4 up to f32 summation order.
// Keeps: reg-prefetch pipeline, key-permuted P/V layouts, strides 68,
// no-max softmax, 128-row Q tiles with A/B row sets.
// ---------------------------------------------------------------------------
#define SKS 68
#define SVS 68
#define SPS 68
__global__ __launch_bounds__(256, 4) void attn_fwd(
    const u16* __restrict__ qkv, const int* __restrict__ cu, u16* __restrict__ out)
{
  __shared__ alignas(16) u16 Ks[64 * SKS];
  __shared__ alignas(16) u16 Vts[64 * SVS];
  __shared__ alignas(16) u16 Ps[8 * 16 * SPS];   // 4 waves x 2 row-sets
  const int seq = blockIdx.z, head = blockIdx.y, qt = blockIdx.x;
  const int start = cu[seq], len = cu[seq + 1] - start;
  const int q0 = qt * 128;
  if (q0 >= len) return;
  const int t = threadIdx.x;
  const int lane = t & 63, wave = t >> 6, quad = lane >> 4, col = lane & 15;

  const int rA = q0 + wave * 16 + col, rB = rA + 64;
  const u16* qpA = qkv + (size_t)(start + (rA < len ? rA : len - 1)) * 3072 + head * 64 + quad * 8;
  const u16* qpB = qkv + (size_t)(start + (rB < len ? rB : len - 1)) * 3072 + head * 64 + quad * 8;
  bf16x8 qfA0 = *(const bf16x8*)qpA;
  bf16x8 qfA1 = *(const bf16x8*)(qpA + 32);
  bf16x8 qfB0 = *(const bf16x8*)qpB;
  bf16x8 qfB1 = *(const bf16x8*)(qpB + 32);

  f32x4_t accOA[4] = {}, accOB[4] = {};
  float lA[4] = {}, lB[4] = {};                  // per-lane partial row sums
  const float SC = 0.125f * 1.44269504089f;

  // staging (r11): sp=t>>3 -> (kc,kh); dc=t&7; key pair (keyA, keyA+16)
  const int sp = t >> 3, dc = t & 7;
  const int kc = sp & 15, kh = sp >> 4;
  const int keyA = kc + 32 * kh;
  u16* ksA = Ks + keyA * SKS + dc * 8;
  u16* ksB = Ks + (keyA + 16) * SKS + dc * 8;
  const int vcol = kc * 4 + 2 * kh;
  const size_t kvbase = 1024 + head * 64 + dc * 8;

  const int nkv = (len + 63) >> 6;
  u32x4_t rkA, rkB, rvA, rvB;
  {   // prologue: tile 0
    int ta = start + (keyA      < len ? keyA      : len - 1);
    int tb = start + (keyA + 16 < len ? keyA + 16 : len - 1);
    const u16* pa = qkv + (size_t)ta * 3072 + kvbase;
    const u16* pb2 = qkv + (size_t)tb * 3072 + kvbase;
    rkA = *(const u32x4*)pa;   rvA = *(const u32x4*)(pa + 1024);
    rkB = *(const u32x4*)pb2;  rvB = *(const u32x4*)(pb2 + 1024);
  }

  for (int it = 0; it < nkv; ++it) {
    const int k0 = it << 6;
    __syncthreads();
    *(u32x4*)ksA = rkA;
    *(u32x4*)ksB = rkB;
    {
      const u16* a = (const u16*)&rvA;
      const u16* b = (const u16*)&rvB;
#pragma unroll
      for (int j = 0; j < 8; ++j) {
        u32 pk = (u32)a[j] | ((u32)b[j] << 16);
        *(u32*)(Vts + (dc * 8 + j) * SVS + vcol) = pk;
      }
    }
    __syncthreads();
    if (it + 1 < nkv) {                          // prefetch next tile
      int kb0 = k0 + 64;
      int ta = start + (kb0 + keyA      < len ? kb0 + keyA      : len - 1);
      int tb = start + (kb0 + keyA + 16 < len ? kb0 + keyA + 16 : len - 1);
      const u16* pa = qkv + (size_t)ta * 3072 + kvbase;
      const u16* pb2 = qkv + (size_t)tb * 3072 + kvbase;
      rkA = *(const u32x4*)pa;   rvA = *(const u32x4*)(pa + 1024);
      rkB = *(const u32x4*)pb2;  rvB = *(const u32x4*)(pb2 + 1024);
    }

    // S = Q.K^T for both row sets (independent chains)
    f32x4_t sgA[4], sgB[4];
#pragma unroll
    for (int g = 0; g < 4; ++g) {
      bf16x8 kb0 = *(const bf16x8*)(Ks + (g*16 + col) * SKS + quad * 8);
      bf16x8 kb1 = *(const bf16x8*)(Ks + (g*16 + col) * SKS + 32 + quad * 8);
      f32x4_t sA = {}, sB = {};
      sA = __builtin_amdgcn_mfma_f32_16x16x32_bf16(qfA0, kb0, sA, 0, 0, 0);
      sB = __builtin_amdgcn_mfma_f32_16x16x32_bf16(qfB0, kb0, sB, 0, 0, 0);
      sA = __builtin_amdgcn_mfma_f32_16x16x32_bf16(qfA1, kb1, sA, 0, 0, 0);
      sB = __builtin_amdgcn_mfma_f32_16x16x32_bf16(qfB1, kb1, sB, 0, 0, 0);
      sgA[g] = sA; sgB[g] = sB;
    }

    // P = exp2(S*SC), masked; key g*16+col -> column col*4+g (b64 rows)
    // L partials accumulate in-register from the SAME rounded bf16 values.
    const bool full = (k0 + 64 <= len);
    bool vg[4];
#pragma unroll
    for (int g = 0; g < 4; ++g) vg[g] = full || (k0 + g*16 + col) < len;
    u16* pwA = Ps + wave * (16 * SPS);
    u16* pwB = Ps + (4 + wave) * (16 * SPS);
#pragma unroll
    for (int r = 0; r < 4; ++r) {
      u16 peA[4], peB[4];
#pragma unroll
      for (int g = 0; g < 4; ++g) {
        float pA = exp2f(sgA[g][r] * SC);
        float pB = exp2f(sgB[g][r] * SC);
        peA[g] = vg[g] ? f2b(pA) : (u16)0;
        peB[g] = vg[g] ? f2b(pB) : (u16)0;
      }
      lA[r] += (b2f(peA[0]) + b2f(peA[1])) + (b2f(peA[2]) + b2f(peA[3]));
      lB[r] += (b2f(peB[0]) + b2f(peB[1])) + (b2f(peB[2]) + b2f(peB[3]));
      u32x2_t wA, wB;
      wA[0] = (u32)peA[0] | ((u32)peA[1] << 16);
      wA[1] = (u32)peA[2] | ((u32)peA[3] << 16);
      wB[0] = (u32)peB[0] | ((u32)peB[1] << 16);
      wB[1] = (u32)peB[2] | ((u32)peB[3] << 16);
      *(u32x2*)(pwA + (quad*4 + r) * SPS + col * 4) = wA;
      *(u32x2*)(pwB + (quad*4 + r) * SPS + col * 4) = wB;
    }
    __threadfence_block();

    bf16x8 pfA0 = *(const bf16x8*)(pwA + col * SPS + quad * 8);
    bf16x8 pfA1 = *(const bf16x8*)(pwA + col * SPS + 32 + quad * 8);
    bf16x8 pfB0 = *(const bf16x8*)(pwB + col * SPS + quad * 8);
    bf16x8 pfB1 = *(const bf16x8*)(pwB + col * SPS + 32 + quad * 8);
#pragma unroll
    for (int c = 0; c < 4; ++c) {
      bf16x8 vf0 = *(const bf16x8*)(Vts + (c*16 + col) * SVS + quad * 8);
      bf16x8 vf1 = *(const bf16x8*)(Vts + (c*16 + col) * SVS + 32 + quad * 8);
      accOA[c] = __builtin_amdgcn_mfma_f32_16x16x32_bf16(pfA0, vf0, accOA[c], 0, 0, 0);
      accOB[c] = __builtin_amdgcn_mfma_f32_16x16x32_bf16(pfB0, vf0, accOB[c], 0, 0, 0);
      accOA[c] = __builtin_amdgcn_mfma_f32_16x16x32_bf16(pfA1, vf1, accOA[c], 0, 0, 0);
      accOB[c] = __builtin_amdgcn_mfma_f32_16x16x32_bf16(pfB1, vf1, accOB[c], 0, 0, 0);
    }
  }

  // epilogue: finish L reduction across the 16 lanes sharing a quad
  // (P[qrow=quad*4+r][key=g*16+col]: cols live on lanes differing in bits 0-3)
#pragma unroll
  for (int r = 0; r < 4; ++r) {
    float sA = lA[r], sB = lB[r];
    sA += __shfl_xor(sA, 1); sB += __shfl_xor(sB, 1);
    sA += __shfl_xor(sA, 2); sB += __shfl_xor(sB, 2);
    sA += __shfl_xor(sA, 4); sB += __shfl_xor(sB, 4);
    sA += __shfl_xor(sA, 8); sB += __shfl_xor(sB, 8);
    int rowA = q0 + wave * 16 + quad * 4 + r;
    int rowB = rowA + 64;
    if (rowA < len) {
      float inv = 1.0f / sA;
      u16* op = out + (size_t)(start + rowA) * 1024 + head * 64 + col;
      op[0]  = f2b(accOA[0][r] * inv);
      op[16] = f2b(accOA[1][r] * inv);
      op[32] = f2b(accOA[2][r] * inv);
      op[48] = f2b(accOA[3][r] * inv);
    }
    if (rowB < len) {
      float inv = 1.0f / sB;
      u16* op = out + (size_t)(start + rowB) * 1024 + head * 64 + col;
      op[0]  = f2b(accOB[0][r] * inv);
      op[16] = f2b(accOB[1][r] * inv);
      op[32] = f2b(accOB[2][r] * inv);
      op[48] = f2b(accOB[3][r] * inv);
    }
  }
}

__global__ void ws_too_small_sentinel(float* out) {
  if (threadIdx.x == 0 && blockIdx.x == 0) out[0] = 1024.0f;
}

// ---------------------------------------------------------------------------
extern "C" void kernel_launch(void* const* d_in, const int* in_sizes, int n_in,
                              void* d_out, int out_size, void* d_ws, size_t ws_size,
                              hipStream_t stream) {
  const float* x  = (const float*)d_in[0];
  const int*   cu = (const int*)d_in[1];
  const float* Wq = (const float*)d_in[2];
  const float* bq = (const float*)d_in[3];
  const float* Wk = (const float*)d_in[4];
  const float* bk = (const float*)d_in[5];
  const float* Wv = (const float*)d_in[6];
  const float* bv = (const float*)d_in[7];
  const float* qn = (const float*)d_in[8];
  const float* kn = (const float*)d_in[9];
  const float* Wo = (const float*)d_in[10];
  const float* bo = (const float*)d_in[11];

  const int T = in_sizes[0] / 1024;
  const int nseq = in_sizes[1] - 1;

  const size_t need_fast = ((size_t)T * 5120 + 4 * WSZ) * 2;   // 92.3 MB @ T=8192
  const size_t need_fall = (size_t)T * 4096 * 2;               // 67.1 MB

  u16* qkv  = (u16*)d_ws;
  u16* attn = qkv + (size_t)T * 3072;
  dim3 blk(256);

  if (ws_size >= need_fast) {
    u16* xb   = attn + (size_t)T * 1024;
    u16* wqkv = xb + (size_t)T * 1024;
    u16* wo   = wqkv + 3 * WSZ;
    cvt_pack<<<dim3(1024), blk, 0, stream>>>(x, Wq, Wk, Wv, Wo, xb, T * 1024);
    gemm_bt2<1, 0><<<dim3((T + 127) / 128, 24), blk, 0, stream>>>(
        xb, wqkv, bq, bk, bv, qn, kn, qkv, T, 1024, 3072);
    attn_fwd<<<dim3(8, 16, nseq), blk, 0, stream>>>(qkv, cu, attn);
    gemm_bt2<0, 1><<<dim3((T + 127) / 128, 8), blk, 0, stream>>>(
        attn, wo, bo, bo, bo, qn, kn, d_out, T, 1024, 1024);
  } else if (ws_size >= need_fall) {
    gemm_bt<1, 0><<<dim3((T + 127) / 128, 24), blk, 0, stream>>>(
        x, Wq, Wk, Wv, bq, bk, bv, qkv, T, 1024, 3072);
    rmsnorm_qk<<<dim3((2 * T * 256 + 255) / 256), blk, 0, stream>>>(qkv, qn, kn, T);
    attn_fwd<<<dim3(8, 16, nseq), blk, 0, stream>>>(qkv, cu, attn);
    gemm_bt<0, 1><<<dim3((T + 127) / 128, 8), blk, 0, stream>>>(
        attn, Wo, Wo, Wo, bo, bo, bo, d_out, T, 1024, 1024);
  } else {
    ws_too_small_sentinel<<<1, 64, 0, stream>>>((float*)d_out);
  }
}

// Round 4
// 266.938 us; speedup vs baseline: 1.1209x; 1.1209x over previous
//
#include <hip/hip_runtime.h>

typedef unsigned short u16;
typedef unsigned int   u32;

typedef __bf16 bf16x8_t __attribute__((ext_vector_type(8)));
typedef bf16x8_t bf16x8 __attribute__((may_alias));
typedef float f32x4_t __attribute__((ext_vector_type(4)));
typedef f32x4_t f32x4 __attribute__((may_alias));
typedef u32 u32x4_t __attribute__((ext_vector_type(4)));
typedef u32x4_t u32x4 __attribute__((may_alias));
typedef u32 u32x2_t __attribute__((ext_vector_type(2)));
typedef u32x2_t u32x2 __attribute__((may_alias));

__device__ __forceinline__ u16 f2b(float f) {        // RNE via hw cvt
  __bf16 h = (__bf16)f; u16 u; __builtin_memcpy(&u, &h, 2); return u;
}
__device__ __forceinline__ float b2f(u16 u) {
  u32 i = ((u32)u) << 16; float f; __builtin_memcpy(&f, &i, 4); return f;
}
__device__ __forceinline__ bf16x8_t cvt8(const float* p) {
  f32x4_t a = *(const f32x4*)p;
  f32x4_t b = *(const f32x4*)(p + 4);
  bf16x8_t v;
  v[0]=(__bf16)a[0]; v[1]=(__bf16)a[1]; v[2]=(__bf16)a[2]; v[3]=(__bf16)a[3];
  v[4]=(__bf16)b[0]; v[5]=(__bf16)b[1]; v[6]=(__bf16)b[2]; v[7]=(__bf16)b[3];
  return v;
}
// async global->LDS, 16B/lane (proper addrspacecast)
typedef __attribute__((address_space(1))) const void* as1cv;
typedef __attribute__((address_space(3))) void* as3v;
__device__ __forceinline__ void gld16(const u16* g, u16* l) {
  __builtin_amdgcn_global_load_lds((as1cv)g, (as3v)l, 16, 0, 0);
}

#define EPS 1.1920929e-07f

// ---------------------------------------------------------------------------
// cvt_pack: x (nx f32) + Wq|Wk|Wv|Wo (1M f32 each) -> bf16 blob (r10)
// ---------------------------------------------------------------------------
#define WSZ (1024 * 1024)
__global__ __launch_bounds__(256) void cvt_pack(
    const float* __restrict__ x, const float* __restrict__ wq,
    const float* __restrict__ wk, const float* __restrict__ wv,
    const float* __restrict__ wo, u16* __restrict__ dst, int nx)
{
  int idx4 = blockIdx.x * 256 + threadIdx.x;
  const int total4 = (nx + 4 * WSZ) >> 2;
  for (; idx4 < total4; idx4 += gridDim.x * 256) {
    int i = idx4 << 2;
    const float* src;
    if (i < nx) src = x + i;
    else {
      int o = i - nx;
      if      (o <     WSZ) src = wq + o;
      else if (o < 2 * WSZ) src = wk + o - WSZ;
      else if (o < 3 * WSZ) src = wv + o - 2 * WSZ;
      else                  src = wo + o - 3 * WSZ;
    }
    f32x4_t v = *(const f32x4*)src;
    u32x2_t p;
    p[0] = (u32)f2b(v[0]) | ((u32)f2b(v[1]) << 16);
    p[1] = (u32)f2b(v[2]) | ((u32)f2b(v[3]) << 16);
    *(u32x2*)(dst + i) = p;
  }
}

// ---------------------------------------------------------------------------
// gemm_bt2 (r10, unchanged): m97 structure + fused RMSNorm epilogue.
// ---------------------------------------------------------------------------
#define BK 32
template<int NORM, int CF32>
__global__ __launch_bounds__(256, 2) void gemm_bt2(
    const u16* __restrict__ A, const u16* __restrict__ Bm,
    const float* __restrict__ bias0, const float* __restrict__ bias1, const float* __restrict__ bias2,
    const float* __restrict__ qn, const float* __restrict__ kn,
    void* __restrict__ C, int M, int K, int ldc)
{
  __shared__ alignas(16) u16 As[128 * BK];
  __shared__ alignas(16) u16 Bs[128 * BK];
  const int t = threadIdx.x;
  const int lane = t & 63, wave = t >> 6;
  const int quad = lane >> 4, col = lane & 15;
  const int m0 = blockIdx.x * 128, n0 = blockIdx.y * 128;
  const int seg = n0 >> 10, nl0 = n0 & 1023;
  const float* bias = seg == 0 ? bias0 : (seg == 1 ? bias1 : bias2);
  const int wm = (wave >> 1) * 64, wn = (wave & 1) * 64;

  const int lrow = t >> 2;
  const int lcol = (t & 3) * 8;
  const u16* ga0 = A  + (size_t)(m0 + lrow) * K + lcol;
  const u16* ga1 = A  + (size_t)(m0 + 64 + lrow) * K + lcol;
  const u16* gb0 = Bm + (size_t)(n0 + lrow) * K + lcol;
  const u16* gb1 = Bm + (size_t)(n0 + 64 + lrow) * K + lcol;
  u16* lA0 = As + t * 8;
  u16* lA1 = As + 64 * BK + t * 8;
  u16* lB0 = Bs + t * 8;
  u16* lB1 = Bs + 64 * BK + t * 8;

  f32x4_t acc[4][4] = {};
  for (int k0 = 0; k0 < K; k0 += BK) {
    __syncthreads();
    gld16(ga0 + k0, lA0);
    gld16(ga1 + k0, lA1);
    gld16(gb0 + k0, lB0);
    gld16(gb1 + k0, lB1);
    __syncthreads();
    bf16x8 af[4], bfr[4];
#pragma unroll
    for (int i = 0; i < 4; ++i) {
      af[i]  = *(const bf16x8*)(As + (wm + i * 16 + col) * BK + quad * 8);
      bfr[i] = *(const bf16x8*)(Bs + (wn + i * 16 + col) * BK + quad * 8);
    }
#pragma unroll
    for (int i = 0; i < 4; ++i)
#pragma unroll
      for (int j = 0; j < 4; ++j)
        acc[i][j] = __builtin_amdgcn_mfma_f32_16x16x32_bf16(af[i], bfr[j], acc[i][j], 0, 0, 0);
  }

  float bz[4], wz[4];
#pragma unroll
  for (int j = 0; j < 4; ++j) {
    bz[j] = bias[nl0 + wn + j * 16 + col];
    if (NORM) wz[j] = (seg == 0 ? qn : kn)[j * 16 + col];
  }
  const bool donorm = NORM && seg < 2;
#pragma unroll
  for (int i = 0; i < 4; ++i) {
#pragma unroll
    for (int rr = 0; rr < 4; ++rr) {
      int gm = m0 + wm + i * 16 + quad * 4 + rr;
      float v[4];
#pragma unroll
      for (int j = 0; j < 4; ++j) v[j] = acc[i][j][rr] + bz[j];
      if (donorm) {
        float ss = v[0]*v[0] + v[1]*v[1] + v[2]*v[2] + v[3]*v[3];
        ss += __shfl_xor(ss, 1);
        ss += __shfl_xor(ss, 2);
        ss += __shfl_xor(ss, 4);
        ss += __shfl_xor(ss, 8);
        float sc = rsqrtf(ss * (1.0f / 64.0f) + EPS);
#pragma unroll
        for (int j = 0; j < 4; ++j) v[j] *= sc * wz[j];
      }
      if (gm < M) {
#pragma unroll
        for (int j = 0; j < 4; ++j) {
          int gn = n0 + wn + j * 16 + col;
          if (CF32) ((float*)C)[(size_t)gm * ldc + gn] = v[j];
          else      ((u16*)C)[(size_t)gm * ldc + gn] = f2b(v[j]);
        }
      }
    }
  }
}

// ---------------------------------------------------------------------------
// FALLBACK tier kernels (r9, unchanged)
// ---------------------------------------------------------------------------
template<int AF32, int CF32>
__global__ __launch_bounds__(256, 2) void gemm_bt(
    const void* __restrict__ Av,
    const float* __restrict__ B0, const float* __restrict__ B1, const float* __restrict__ B2,
    const float* __restrict__ bias0, const float* __restrict__ bias1, const float* __restrict__ bias2,
    void* __restrict__ C, int M, int K, int ldc)
{
  __shared__ alignas(16) u16 As[128 * BK];
  __shared__ alignas(16) u16 Bs[128 * BK];
  const int t = threadIdx.x;
  const int lane = t & 63, wave = t >> 6;
  const int quad = lane >> 4, col = lane & 15;
  const int m0 = blockIdx.x * 128, n0 = blockIdx.y * 128;
  const int seg = n0 >> 10;
  const float* B    = seg == 0 ? B0    : (seg == 1 ? B1    : B2);
  const float* bias = seg == 0 ? bias0 : (seg == 1 ? bias1 : bias2);
  const int nl0 = n0 & 1023;
  const int wm = (wave >> 1) * 64, wn = (wave & 1) * 64;
  const int lrow = t >> 2;
  const int lcol = (t & 3) * 8;
  int ar0 = m0 + lrow;      if (ar0 >= M) ar0 = M - 1;
  int ar1 = m0 + 64 + lrow; if (ar1 >= M) ar1 = M - 1;
  const float* bp0 = B + (size_t)(nl0 + lrow) * K + lcol;
  const float* bp1 = B + (size_t)(nl0 + 64 + lrow) * K + lcol;
  const float* apf0 = (const float*)Av + (size_t)ar0 * K + lcol;
  const float* apf1 = (const float*)Av + (size_t)ar1 * K + lcol;
  const u16*   aph0 = (const u16*)Av   + (size_t)ar0 * K + lcol;
  const u16*   aph1 = (const u16*)Av   + (size_t)ar1 * K + lcol;
  u16* lA0 = As + t * 8;
  u16* lA1 = As + 64 * BK + t * 8;
  u16* lB0 = Bs + t * 8;
  u16* lB1 = Bs + 64 * BK + t * 8;

  f32x4_t acc[4][4] = {};
  for (int k0 = 0; k0 < K; k0 += BK) {
    bf16x8_t va0, va1, vb0, vb1;
    if (AF32) { va0 = cvt8(apf0 + k0); va1 = cvt8(apf1 + k0); }
    else {
      u32x4_t r0 = *(const u32x4*)(aph0 + k0);
      u32x4_t r1 = *(const u32x4*)(aph1 + k0);
      __builtin_memcpy(&va0, &r0, 16);
      __builtin_memcpy(&va1, &r1, 16);
    }
    vb0 = cvt8(bp0 + k0);
    vb1 = cvt8(bp1 + k0);
    __syncthreads();
    *(bf16x8*)lA0 = va0; *(bf16x8*)lA1 = va1;
    *(bf16x8*)lB0 = vb0; *(bf16x8*)lB1 = vb1;
    __syncthreads();
    bf16x8 af[4], bfr[4];
#pragma unroll
    for (int i = 0; i < 4; ++i) {
      af[i]  = *(const bf16x8*)(As + (wm + i * 16 + col) * BK + quad * 8);
      bfr[i] = *(const bf16x8*)(Bs + (wn + i * 16 + col) * BK + quad * 8);
    }
#pragma unroll
    for (int i = 0; i < 4; ++i)
#pragma unroll
      for (int j = 0; j < 4; ++j)
        acc[i][j] = __builtin_amdgcn_mfma_f32_16x16x32_bf16(af[i], bfr[j], acc[i][j], 0, 0, 0);
  }
#pragma unroll
  for (int j = 0; j < 4; ++j) {
    int gn = n0 + wn + j * 16 + col;
    float bz = bias[nl0 + wn + j * 16 + col];
#pragma unroll
    for (int i = 0; i < 4; ++i) {
#pragma unroll
      for (int rr = 0; rr < 4; ++rr) {
        int gm = m0 + wm + i * 16 + quad * 4 + rr;
        if (gm < M) {
          float v = acc[i][j][rr] + bz;
          if (CF32) ((float*)C)[(size_t)gm * ldc + gn] = v;
          else      ((u16*)C)[(size_t)gm * ldc + gn] = f2b(v);
        }
      }
    }
  }
}

__global__ __launch_bounds__(256) void rmsnorm_qk(
    u16* __restrict__ qkv, const float* __restrict__ qn, const float* __restrict__ kn, int T)
{
  int gid = blockIdx.x * 256 + threadIdx.x;
  int row = gid >> 4, sub = gid & 15;
  if (row >= 2 * T * 16) return;
  int which = row >= T * 16;
  int r = which ? row - T * 16 : row;
  int tok = r >> 4, head = r & 15;
  u16* p = qkv + (size_t)tok * 3072 + which * 1024 + head * 64 + sub * 4;
  u16 d0 = p[0], d1 = p[1], d2 = p[2], d3 = p[3];
  float f0 = b2f(d0), f1 = b2f(d1), f2v = b2f(d2), f3 = b2f(d3);
  float ss = f0 * f0 + f1 * f1 + f2v * f2v + f3 * f3;
  ss += __shfl_xor(ss, 1);
  ss += __shfl_xor(ss, 2);
  ss += __shfl_xor(ss, 4);
  ss += __shfl_xor(ss, 8);
  float sc = rsqrtf(ss * (1.0f / 64.0f) + EPS);
  const float* w = which ? kn : qn;
  p[0] = f2b(f0 * sc * w[sub * 4 + 0]);
  p[1] = f2b(f1 * sc * w[sub * 4 + 1]);
  p[2] = f2b(f2v * sc * w[sub * 4 + 2]);
  p[3] = f2b(f3 * sc * w[sub * 4 + 3]);
}

// ---------------------------------------------------------------------------
// Flash attention v6 (3rd submit; rounds 1-2 broker-timed-out): v5 compute,
// grid is HEAD-MAJOR.
// Old grid (qt=x,head=y,seq=z) gave linear id % 8 == qt, so with round-robin
// workgroup->XCD assignment each XCD owned ONE qt value. Since qt>=6 is dead
// for len=768 and qt>=2 dead for len=256, XCDs 6-7 sat idle and XCDs 0-1
// carried 1.6x the average work (rocprof r0: Occupancy 18.6%, MfmaUtil 7.2%,
// VALU 28.6% -- everything idle on average = a few CUs on the critical path).
// New grid (head=x,qt=y,seq=z): id % 8 == head % 8 -> every XCD gets 2 heads
// x all qt x all seqs: live/dead and long/short perfectly balanced, AND all
// qt-tiles of one (seq,head) land on the same XCD -> K/V L2 reuse across qt
// (r0 FETCH 90MB vs ~50MB ideal was cross-XCD KV re-fetch).
// ---------------------------------------------------------------------------
#define SKS 68
#define SVS 68
#define SPS 68
__global__ __launch_bounds__(256, 4) void attn_fwd(
    const u16* __restrict__ qkv, const int* __restrict__ cu, u16* __restrict__ out)
{
  __shared__ alignas(16) u16 Ks[64 * SKS];
  __shared__ alignas(16) u16 Vts[64 * SVS];
  __shared__ alignas(16) u16 Ps[8 * 16 * SPS];   // 4 waves x 2 row-sets
  const int seq = blockIdx.z, head = blockIdx.x, qt = blockIdx.y;
  const int start = cu[seq], len = cu[seq + 1] - start;
  const int q0 = qt * 128;
  if (q0 >= len) return;
  const int t = threadIdx.x;
  const int lane = t & 63, wave = t >> 6, quad = lane >> 4, col = lane & 15;

  const int rA = q0 + wave * 16 + col, rB = rA + 64;
  const u16* qpA = qkv + (size_t)(start + (rA < len ? rA : len - 1)) * 3072 + head * 64 + quad * 8;
  const u16* qpB = qkv + (size_t)(start + (rB < len ? rB : len - 1)) * 3072 + head * 64 + quad * 8;
  bf16x8 qfA0 = *(const bf16x8*)qpA;
  bf16x8 qfA1 = *(const bf16x8*)(qpA + 32);
  bf16x8 qfB0 = *(const bf16x8*)qpB;
  bf16x8 qfB1 = *(const bf16x8*)(qpB + 32);

  f32x4_t accOA[4] = {}, accOB[4] = {};
  float lA[4] = {}, lB[4] = {};                  // per-lane partial row sums
  const float SC = 0.125f * 1.44269504089f;

  // staging (r11): sp=t>>3 -> (kc,kh); dc=t&7; key pair (keyA, keyA+16)
  const int sp = t >> 3, dc = t & 7;
  const int kc = sp & 15, kh = sp >> 4;
  const int keyA = kc + 32 * kh;
  u16* ksA = Ks + keyA * SKS + dc * 8;
  u16* ksB = Ks + (keyA + 16) * SKS + dc * 8;
  const int vcol = kc * 4 + 2 * kh;
  const size_t kvbase = 1024 + head * 64 + dc * 8;

  const int nkv = (len + 63) >> 6;
  u32x4_t rkA, rkB, rvA, rvB;
  {   // prologue: tile 0
    int ta = start + (keyA      < len ? keyA      : len - 1);
    int tb = start + (keyA + 16 < len ? keyA + 16 : len - 1);
    const u16* pa = qkv + (size_t)ta * 3072 + kvbase;
    const u16* pb2 = qkv + (size_t)tb * 3072 + kvbase;
    rkA = *(const u32x4*)pa;   rvA = *(const u32x4*)(pa + 1024);
    rkB = *(const u32x4*)pb2;  rvB = *(const u32x4*)(pb2 + 1024);
  }

  for (int it = 0; it < nkv; ++it) {
    const int k0 = it << 6;
    __syncthreads();
    *(u32x4*)ksA = rkA;
    *(u32x4*)ksB = rkB;
    {
      const u16* a = (const u16*)&rvA;
      const u16* b = (const u16*)&rvB;
#pragma unroll
      for (int j = 0; j < 8; ++j) {
        u32 pk = (u32)a[j] | ((u32)b[j] << 16);
        *(u32*)(Vts + (dc * 8 + j) * SVS + vcol) = pk;
      }
    }
    __syncthreads();
    if (it + 1 < nkv) {                          // prefetch next tile
      int kb0 = k0 + 64;
      int ta = start + (kb0 + keyA      < len ? kb0 + keyA      : len - 1);
      int tb = start + (kb0 + keyA + 16 < len ? kb0 + keyA + 16 : len - 1);
      const u16* pa = qkv + (size_t)ta * 3072 + kvbase;
      const u16* pb2 = qkv + (size_t)tb * 3072 + kvbase;
      rkA = *(const u32x4*)pa;   rvA = *(const u32x4*)(pa + 1024);
      rkB = *(const u32x4*)pb2;  rvB = *(const u32x4*)(pb2 + 1024);
    }

    // S = Q.K^T for both row sets (independent chains)
    f32x4_t sgA[4], sgB[4];
#pragma unroll
    for (int g = 0; g < 4; ++g) {
      bf16x8 kb0 = *(const bf16x8*)(Ks + (g*16 + col) * SKS + quad * 8);
      bf16x8 kb1 = *(const bf16x8*)(Ks + (g*16 + col) * SKS + 32 + quad * 8);
      f32x4_t sA = {}, sB = {};
      sA = __builtin_amdgcn_mfma_f32_16x16x32_bf16(qfA0, kb0, sA, 0, 0, 0);
      sB = __builtin_amdgcn_mfma_f32_16x16x32_bf16(qfB0, kb0, sB, 0, 0, 0);
      sA = __builtin_amdgcn_mfma_f32_16x16x32_bf16(qfA1, kb1, sA, 0, 0, 0);
      sB = __builtin_amdgcn_mfma_f32_16x16x32_bf16(qfB1, kb1, sB, 0, 0, 0);
      sgA[g] = sA; sgB[g] = sB;
    }

    // P = exp2(S*SC), masked; key g*16+col -> column col*4+g (b64 rows)
    // L partials accumulate in-register from the SAME rounded bf16 values.
    const bool full = (k0 + 64 <= len);
    bool vg[4];
#pragma unroll
    for (int g = 0; g < 4; ++g) vg[g] = full || (k0 + g*16 + col) < len;
    u16* pwA = Ps + wave * (16 * SPS);
    u16* pwB = Ps + (4 + wave) * (16 * SPS);
#pragma unroll
    for (int r = 0; r < 4; ++r) {
      u16 peA[4], peB[4];
#pragma unroll
      for (int g = 0; g < 4; ++g) {
        float pA = exp2f(sgA[g][r] * SC);
        float pB = exp2f(sgB[g][r] * SC);
        peA[g] = vg[g] ? f2b(pA) : (u16)0;
        peB[g] = vg[g] ? f2b(pB) : (u16)0;
      }
      lA[r] += (b2f(peA[0]) + b2f(peA[1])) + (b2f(peA[2]) + b2f(peA[3]));
      lB[r] += (b2f(peB[0]) + b2f(peB[1])) + (b2f(peB[2]) + b2f(peB[3]));
      u32x2_t wA, wB;
      wA[0] = (u32)peA[0] | ((u32)peA[1] << 16);
      wA[1] = (u32)peA[2] | ((u32)peA[3] << 16);
      wB[0] = (u32)peB[0] | ((u32)peB[1] << 16);
      wB[1] = (u32)peB[2] | ((u32)peB[3] << 16);
      *(u32x2*)(pwA + (quad*4 + r) * SPS + col * 4) = wA;
      *(u32x2*)(pwB + (quad*4 + r) * SPS + col * 4) = wB;
    }
    __threadfence_block();

    bf16x8 pfA0 = *(const bf16x8*)(pwA + col * SPS + quad * 8);
    bf16x8 pfA1 = *(const bf16x8*)(pwA + col * SPS + 32 + quad * 8);
    bf16x8 pfB0 = *(const bf16x8*)(pwB + col * SPS + quad * 8);
    bf16x8 pfB1 = *(const bf16x8*)(pwB + col * SPS + 32 + quad * 8);
#pragma unroll
    for (int c = 0; c < 4; ++c) {
      bf16x8 vf0 = *(const bf16x8*)(Vts + (c*16 + col) * SVS + quad * 8);
      bf16x8 vf1 = *(const bf16x8*)(Vts + (c*16 + col) * SVS + 32 + quad * 8);
      accOA[c] = __builtin_amdgcn_mfma_f32_16x16x32_bf16(pfA0, vf0, accOA[c], 0, 0, 0);
      accOB[c] = __builtin_amdgcn_mfma_f32_16x16x32_bf16(pfB0, vf0, accOB[c], 0, 0, 0);
      accOA[c] = __builtin_amdgcn_mfma_f32_16x16x32_bf16(pfA1, vf1, accOA[c], 0, 0, 0);
      accOB[c] = __builtin_amdgcn_mfma_f32_16x16x32_bf16(pfB1, vf1, accOB[c], 0, 0, 0);
    }
  }

  // epilogue: finish L reduction across the 16 lanes sharing a quad
  // (P[qrow=quad*4+r][key=g*16+col]: cols live on lanes differing in bits 0-3)
#pragma unroll
  for (int r = 0; r < 4; ++r) {
    float sA = lA[r], sB = lB[r];
    sA += __shfl_xor(sA, 1); sB += __shfl_xor(sB, 1);
    sA += __shfl_xor(sA, 2); sB += __shfl_xor(sB, 2);
    sA += __shfl_xor(sA, 4); sB += __shfl_xor(sB, 4);
    sA += __shfl_xor(sA, 8); sB += __shfl_xor(sB, 8);
    int rowA = q0 + wave * 16 + quad * 4 + r;
    int rowB = rowA + 64;
    if (rowA < len) {
      float inv = 1.0f / sA;
      u16* op = out + (size_t)(start + rowA) * 1024 + head * 64 + col;
      op[0]  = f2b(accOA[0][r] * inv);
      op[16] = f2b(accOA[1][r] * inv);
      op[32] = f2b(accOA[2][r] * inv);
      op[48] = f2b(accOA[3][r] * inv);
    }
    if (rowB < len) {
      float inv = 1.0f / sB;
      u16* op = out + (size_t)(start + rowB) * 1024 + head * 64 + col;
      op[0]  = f2b(accOB[0][r] * inv);
      op[16] = f2b(accOB[1][r] * inv);
      op[32] = f2b(accOB[2][r] * inv);
      op[48] = f2b(accOB[3][r] * inv);
    }
  }
}

__global__ void ws_too_small_sentinel(float* out) {
  if (threadIdx.x == 0 && blockIdx.x == 0) out[0] = 1024.0f;
}

// ---------------------------------------------------------------------------
extern "C" void kernel_launch(void* const* d_in, const int* in_sizes, int n_in,
                              void* d_out, int out_size, void* d_ws, size_t ws_size,
                              hipStream_t stream) {
  const float* x  = (const float*)d_in[0];
  const int*   cu = (const int*)d_in[1];
  const float* Wq = (const float*)d_in[2];
  const float* bq = (const float*)d_in[3];
  const float* Wk = (const float*)d_in[4];
  const float* bk = (const float*)d_in[5];
  const float* Wv = (const float*)d_in[6];
  const float* bv = (const float*)d_in[7];
  const float* qn = (const float*)d_in[8];
  const float* kn = (const float*)d_in[9];
  const float* Wo = (const float*)d_in[10];
  const float* bo = (const float*)d_in[11];

  const int T = in_sizes[0] / 1024;
  const int nseq = in_sizes[1] - 1;

  const size_t need_fast = ((size_t)T * 5120 + 4 * WSZ) * 2;   // 92.3 MB @ T=8192
  const size_t need_fall = (size_t)T * 4096 * 2;               // 67.1 MB

  u16* qkv  = (u16*)d_ws;
  u16* attn = qkv + (size_t)T * 3072;
  dim3 blk(256);

  if (ws_size >= need_fast) {
    u16* xb   = attn + (size_t)T * 1024;
    u16* wqkv = xb + (size_t)T * 1024;
    u16* wo   = wqkv + 3 * WSZ;
    cvt_pack<<<dim3(1024), blk, 0, stream>>>(x, Wq, Wk, Wv, Wo, xb, T * 1024);
    gemm_bt2<1, 0><<<dim3((T + 127) / 128, 24), blk, 0, stream>>>(
        xb, wqkv, bq, bk, bv, qn, kn, qkv, T, 1024, 3072);
    attn_fwd<<<dim3(16, 8, nseq), blk, 0, stream>>>(qkv, cu, attn);
    gemm_bt2<0, 1><<<dim3((T + 127) / 128, 8), blk, 0, stream>>>(
        attn, wo, bo, bo, bo, qn, kn, d_out, T, 1024, 1024);
  } else if (ws_size >= need_fall) {
    gemm_bt<1, 0><<<dim3((T + 127) / 128, 24), blk, 0, stream>>>(
        x, Wq, Wk, Wv, bq, bk, bv, qkv, T, 1024, 3072);
    rmsnorm_qk<<<dim3((2 * T * 256 + 255) / 256), blk, 0, stream>>>(qkv, qn, kn, T);
    attn_fwd<<<dim3(16, 8, nseq), blk, 0, stream>>>(qkv, cu, attn);
    gemm_bt<0, 1><<<dim3((T + 127) / 128, 8), blk, 0, stream>>>(
        attn, Wo, Wo, Wo, bo, bo, bo, d_out, T, 1024, 1024);
  } else {
    ws_too_small_sentinel<<<1, 64, 0, stream>>>((float*)d_out);
  }
}